// Round 1
// baseline (276.723 us; speedup 1.0000x reference)
//
#include <hip/hip_runtime.h>

// apool: input (512, 2048, 7, 7) fp32, viewed as 1,048,576 rows x 49 floats.
// Per row: mean of top-4 elements. Output (512, 2048, 1, 1) fp32.
//
// Memory-bound (~210 MB traffic, ~6x over VALU cost). Strategy:
//  - 256 threads/block stage 256 contiguous rows (12544 floats = 49 KiB)
//    into LDS via coalesced float4 loads.
//  - each thread then scans its own 49-element row from LDS with a
//    branchless top-4 insertion network (min/max sorting chain).
//  - LDS access: lane t elem i -> bank (17t+i)%32, exactly 2-way over 64
//    lanes => conflict-free per m136.

#define ROW_LEN 49
#define ROWS_PER_BLOCK 256
#define BLOCK_THREADS 256
#define FLOATS_PER_BLOCK (ROWS_PER_BLOCK * ROW_LEN)   // 12544
#define VEC4_PER_BLOCK (FLOATS_PER_BLOCK / 4)         // 3136

__global__ __launch_bounds__(BLOCK_THREADS)
void apool_52286931861675_kernel(const float* __restrict__ x,
                                 float* __restrict__ out) {
    __shared__ float lds[FLOATS_PER_BLOCK];  // 50176 B -> 3 blocks/CU

    // Coalesced global -> LDS staging, float4 (16B) per lane.
    // Block base float index = blockIdx.x * 12544, divisible by 4 -> 16B aligned.
    const float4* __restrict__ src =
        (const float4*)(x + (size_t)blockIdx.x * FLOATS_PER_BLOCK);
    float4* dst = (float4*)lds;
    #pragma unroll
    for (int i = 0; i < 13; ++i) {
        int idx = (int)threadIdx.x + i * BLOCK_THREADS;
        if (idx < VEC4_PER_BLOCK) dst[idx] = src[idx];
    }
    __syncthreads();

    // Each thread: top-4 of its own row via branchless insertion network.
    const float* row = lds + (size_t)threadIdx.x * ROW_LEN;
    float m0 = -__builtin_inff();
    float m1 = m0, m2 = m0, m3 = m0;
    #pragma unroll
    for (int i = 0; i < ROW_LEN; ++i) {
        float v  = row[i];
        float t0 = fminf(m0, v);  m0 = fmaxf(m0, v);
        float t1 = fminf(m1, t0); m1 = fmaxf(m1, t0);
        float t2 = fminf(m2, t1); m2 = fmaxf(m2, t1);
        m3 = fmaxf(m3, t2);
    }

    out[(size_t)blockIdx.x * ROWS_PER_BLOCK + threadIdx.x] =
        (m0 + m1 + m2 + m3) * 0.25f;
}

extern "C" void kernel_launch(void* const* d_in, const int* in_sizes, int n_in,
                              void* d_out, int out_size, void* d_ws, size_t ws_size,
                              hipStream_t stream) {
    const float* x = (const float*)d_in[0];   // (512, 2048, 7, 7) fp32
    float* out = (float*)d_out;               // (512, 2048, 1, 1) fp32

    const int rows = out_size;                // 512*2048 = 1,048,576 (divisible by 256)
    const int grid = rows / ROWS_PER_BLOCK;   // 4096 blocks

    apool_52286931861675_kernel<<<grid, BLOCK_THREADS, 0, stream>>>(x, out);
}

// Round 2
// 276.270 us; speedup vs baseline: 1.0016x; 1.0016x over previous
//
#include <hip/hip_runtime.h>
#include <float.h>

// apool: input (512, 2048, 7, 7) fp32 = 1,048,576 rows x 49 floats.
// Per row: mean of top-4. Output (512, 2048, 1, 1) fp32. Memory-bound.
//
// R2 design: 4 threads per row.
//  - 256 threads/block -> 64 rows/block, LDS = 64*49*4 = 12.5 KiB
//    -> 8 blocks/CU = 32 waves/CU (max occupancy; was 3 blocks/12 waves).
//  - staging: 784 float4 coalesced loads (4 per thread, independent -> MLP).
//  - each thread: top-4 insertion over its ~13-element quarter-row (LDS).
//  - two __shfl_xor merge rounds (xor 1, xor 2) combine quarters in-wave.
//  - lane with q==0 writes the row's result.

#define ROW_LEN 49
#define ROWS_PER_BLOCK 64
#define BLOCK_THREADS 256
#define FLOATS_PER_BLOCK (ROWS_PER_BLOCK * ROW_LEN)   // 3136
#define VEC4_PER_BLOCK (FLOATS_PER_BLOCK / 4)         // 784

__device__ __forceinline__ void top4_insert(float v, float& m0, float& m1,
                                            float& m2, float& m3) {
    float t0 = fminf(m0, v);  m0 = fmaxf(m0, v);
    float t1 = fminf(m1, t0); m1 = fmaxf(m1, t0);
    float t2 = fminf(m2, t1); m2 = fmaxf(m2, t1);
    m3 = fmaxf(m3, t2);
}

__global__ __launch_bounds__(BLOCK_THREADS, 8)
void apool_52286931861675_kernel(const float* __restrict__ x,
                                 float* __restrict__ out) {
    __shared__ float lds[FLOATS_PER_BLOCK];  // 12544 B -> 8 blocks/CU

    // Coalesced global -> LDS staging. Block base = blockIdx.x*12544 B,
    // 16B-aligned (12544 % 16 == 0).
    const float4* __restrict__ src =
        (const float4*)(x + (size_t)blockIdx.x * FLOATS_PER_BLOCK);
    float4* dst = (float4*)lds;
    #pragma unroll
    for (int i = 0; i < 4; ++i) {
        int idx = (int)threadIdx.x + i * BLOCK_THREADS;
        if (idx < VEC4_PER_BLOCK) dst[idx] = src[idx];
    }
    __syncthreads();

    // Quarter-row partition: 49 = 13 + 12 + 12 + 12.
    const int r = threadIdx.x >> 2;      // row within block
    const int q = threadIdx.x & 3;       // quarter index
    const int start = (q == 0) ? 0 : (1 + 12 * q);   // {0,13,25,37}
    const int cnt   = (q == 0) ? 13 : 12;
    const float* row = lds + r * ROW_LEN;

    const float NEG = -FLT_MAX;
    float m0 = NEG, m1 = NEG, m2 = NEG, m3 = NEG;
    #pragma unroll
    for (int i = 0; i < 13; ++i) {
        // sentinel pad for the 12-element quarters (branchless; inputs are
        // finite normals, so -FLT_MAX can never displace real top-4 entries)
        float v = (i < cnt) ? row[start + i] : NEG;
        top4_insert(v, m0, m1, m2, m3);
    }

    // Butterfly merge across the 4 lanes of this row (wave-internal).
    #pragma unroll
    for (int k = 1; k <= 2; k <<= 1) {
        float p0 = __shfl_xor(m0, k);
        float p1 = __shfl_xor(m1, k);
        float p2 = __shfl_xor(m2, k);
        float p3 = __shfl_xor(m3, k);
        top4_insert(p0, m0, m1, m2, m3);
        top4_insert(p1, m0, m1, m2, m3);
        top4_insert(p2, m0, m1, m2, m3);
        top4_insert(p3, m0, m1, m2, m3);
    }

    if (q == 0) {
        out[(size_t)blockIdx.x * ROWS_PER_BLOCK + r] =
            (m0 + m1 + m2 + m3) * 0.25f;
    }
}

extern "C" void kernel_launch(void* const* d_in, const int* in_sizes, int n_in,
                              void* d_out, int out_size, void* d_ws, size_t ws_size,
                              hipStream_t stream) {
    const float* x = (const float*)d_in[0];   // (512, 2048, 7, 7) fp32
    float* out = (float*)d_out;               // (512, 2048, 1, 1) fp32

    const int rows = out_size;                // 1,048,576 (divisible by 64)
    const int grid = rows / ROWS_PER_BLOCK;   // 16384 blocks

    apool_52286931861675_kernel<<<grid, BLOCK_THREADS, 0, stream>>>(x, out);
}